// Round 1
// baseline (10035.152 us; speedup 1.0000x reference)
//
#include <hip/hip_runtime.h>
#include <math.h>

#define Bb 256
#define Tt 512
#define Ii 128
#define Hh 256
#define Ss 4
#define G4 1024  // 4*H gate rows

// ---------------- kernel 1: lengths[b] = max(sum(mask[b,:]), 1) ----------------
__global__ void k_len(const int* __restrict__ mask, int* __restrict__ len) {
  int b = blockIdx.x, tid = threadIdx.x;
  int c = (mask[b * Tt + tid] != 0) + (mask[b * Tt + 256 + tid] != 0);
#pragma unroll
  for (int off = 32; off > 0; off >>= 1) c += __shfl_down(c, off, 64);
  __shared__ int red[4];
  if ((tid & 63) == 0) red[tid >> 6] = c;
  __syncthreads();
  if (tid == 0) {
    int t = red[0] + red[1] + red[2] + red[3];
    len[b] = t < 1 ? 1 : t;
  }
}

// ---------------- kernel 2: transpose weights into [s][i/4][o] float4 layout ----
// wt_hh[(s*64 + i4)*1024 + o] = {W_hh[s][o][4i4..4i4+3]}
// wt_ih[(s*32 + i4)*1024 + o] = {W_ih[s][o][4i4..4i4+3]}
__global__ void k_tr(const float* __restrict__ W_ih, const float* __restrict__ W_hh,
                     float4* __restrict__ wt_hh, float4* __restrict__ wt_ih) {
  int id = blockIdx.x * blockDim.x + threadIdx.x;
  const int NHH = Ss * 64 * G4;
  const int NIH = Ss * 32 * G4;
  if (id < NHH) {
    int o = id % G4, i4 = (id / G4) % 64, s = id / (G4 * 64);
    wt_hh[id] = *(const float4*)(W_hh + ((size_t)(s * G4 + o)) * Hh + 4 * i4);
  } else if (id < NHH + NIH) {
    int id2 = id - NHH;
    int o = id2 % G4, i4 = (id2 / G4) % 32, s = id2 / (G4 * 32);
    wt_ih[id2] = *(const float4*)(W_ih + ((size_t)(s * G4 + o)) * Ii + 4 * i4);
  }
}

// ---------------- kernel 3: gx[b][t][o] = W_ih[seg]@x + b_ih[seg]+b_hh[seg] ----
// One block per (b, 32-t chunk). Thread tid owns o0=tid and its 4 gate rows.
__global__ __launch_bounds__(256, 2) void k_gx(
    const float* __restrict__ x, const float4* __restrict__ wt_ih,
    const float* __restrict__ b_ih, const float* __restrict__ b_hh,
    const int* __restrict__ len, float* __restrict__ gx) {
  const int b = blockIdx.x >> 4;
  const int t0 = (blockIdx.x & 15) * 32;
  const int tid = threadIdx.x;
  const int L = len[b];
  if (t0 >= L) return;  // gx never read for t >= L
  __shared__ __align__(16) float xs[32 * Ii];
  __shared__ int segt[32];
  float4* xs4 = (float4*)xs;
  const float4* xsrc = (const float4*)(x + ((size_t)b * Tt + t0) * Ii);
  for (int f = tid; f < 32 * 32; f += 256) xs4[f] = xsrc[f];
  if (tid < 32) {
    int s = (t0 + tid) * Ss / L;
    segt[tid] = s > Ss - 1 ? Ss - 1 : s;
  }
  __syncthreads();
  const int s_lo = segt[0];
  const int s_hi = segt[31];
  for (int s = s_lo; s <= s_hi; s++) {
    float acc[4][32];
#pragma unroll
    for (int g = 0; g < 4; g++)
#pragma unroll
      for (int t = 0; t < 32; t++) acc[g][t] = 0.f;
    const float4* wb = wt_ih + (size_t)s * 32 * G4 + tid;
    for (int i4 = 0; i4 < 32; i4++) {
      float4 w0 = wb[i4 * G4];
      float4 w1 = wb[i4 * G4 + 256];
      float4 w2 = wb[i4 * G4 + 512];
      float4 w3 = wb[i4 * G4 + 768];
#pragma unroll
      for (int t = 0; t < 32; t++) {
        float4 hv = xs4[t * 32 + i4];
        acc[0][t] += w0.x * hv.x + w0.y * hv.y + w0.z * hv.z + w0.w * hv.w;
        acc[1][t] += w1.x * hv.x + w1.y * hv.y + w1.z * hv.z + w1.w * hv.w;
        acc[2][t] += w2.x * hv.x + w2.y * hv.y + w2.z * hv.z + w2.w * hv.w;
        acc[3][t] += w3.x * hv.x + w3.y * hv.y + w3.z * hv.z + w3.w * hv.w;
      }
    }
    float bsum[4];
#pragma unroll
    for (int g = 0; g < 4; g++)
      bsum[g] = b_ih[s * G4 + g * 256 + tid] + b_hh[s * G4 + g * 256 + tid];
#pragma unroll
    for (int t = 0; t < 32; t++) {
      if (segt[t] == s) {
        size_t base = ((size_t)b * Tt + t0 + t) * G4 + tid;
#pragma unroll
        for (int g = 0; g < 4; g++) gx[base + g * 256] = acc[g][t] + bsum[g];
      }
    }
  }
}

// ---------------- kernel 4: the recurrence. One block per batch. ---------------
// Thread j owns h-unit j: gate rows j, 256+j, 512+j, 768+j. h in LDS, c in reg.
template <bool USE_GX>
__global__ __launch_bounds__(256, 1) void k_lstm(
    const float* __restrict__ x, const float4* __restrict__ wt_hh,
    const float4* __restrict__ wt_ih, const float* __restrict__ b_ih,
    const float* __restrict__ b_hh, const int* __restrict__ len,
    const float* __restrict__ gx, float* __restrict__ out) {
  const int b = blockIdx.x;
  const int j = threadIdx.x;
  __shared__ __align__(16) float h_sh[Hh];
  __shared__ __align__(16) float xs[Ii];
  h_sh[j] = 0.f;
  float c = 0.f;
  const int L = len[b];
  float* outb = out + (size_t)b * Tt * Hh;
  float* lastb = out + (size_t)Bb * Tt * Hh + (size_t)b * Hh;
  const float4* h4 = (const float4*)h_sh;
  for (int t = 0; t < Tt; t++) {
    if (t < L) {  // uniform per block
      int s = t * Ss / L;
      if (s > Ss - 1) s = Ss - 1;
      float ai, af, ag, ao;
      if (USE_GX) {
        const float* g = gx + ((size_t)b * Tt + t) * G4;
        ai = g[j]; af = g[j + 256]; ag = g[j + 512]; ao = g[j + 768];
      } else {
        if (j < 32)
          ((float4*)xs)[j] = ((const float4*)(x + ((size_t)b * Tt + t) * Ii))[j];
        const float* bi = b_ih + s * G4;
        const float* bh = b_hh + s * G4;
        ai = bi[j] + bh[j];
        af = bi[j + 256] + bh[j + 256];
        ag = bi[j + 512] + bh[j + 512];
        ao = bi[j + 768] + bh[j + 768];
      }
      // barrier #1: prev-iter h_sh writes (and x staging) visible
      __syncthreads();
      const float4* wb = wt_hh + (size_t)s * 64 * G4 + j;
#pragma unroll 8
      for (int i4 = 0; i4 < 64; i4++) {
        float4 hv = h4[i4];  // wave-uniform broadcast
        float4 w0 = wb[i4 * G4];
        float4 w1 = wb[i4 * G4 + 256];
        float4 w2 = wb[i4 * G4 + 512];
        float4 w3 = wb[i4 * G4 + 768];
        ai += w0.x * hv.x + w0.y * hv.y + w0.z * hv.z + w0.w * hv.w;
        af += w1.x * hv.x + w1.y * hv.y + w1.z * hv.z + w1.w * hv.w;
        ag += w2.x * hv.x + w2.y * hv.y + w2.z * hv.z + w2.w * hv.w;
        ao += w3.x * hv.x + w3.y * hv.y + w3.z * hv.z + w3.w * hv.w;
      }
      if (!USE_GX) {
        const float4* wbi = wt_ih + (size_t)s * 32 * G4 + j;
        const float4* x4 = (const float4*)xs;
#pragma unroll 8
        for (int i4 = 0; i4 < 32; i4++) {
          float4 hv = x4[i4];
          float4 w0 = wbi[i4 * G4];
          float4 w1 = wbi[i4 * G4 + 256];
          float4 w2 = wbi[i4 * G4 + 512];
          float4 w3 = wbi[i4 * G4 + 768];
          ai += w0.x * hv.x + w0.y * hv.y + w0.z * hv.z + w0.w * hv.w;
          af += w1.x * hv.x + w1.y * hv.y + w1.z * hv.z + w1.w * hv.w;
          ag += w2.x * hv.x + w2.y * hv.y + w2.z * hv.z + w2.w * hv.w;
          ao += w3.x * hv.x + w3.y * hv.y + w3.z * hv.z + w3.w * hv.w;
        }
      }
      float ig = 1.f / (1.f + expf(-ai));
      float fg = 1.f / (1.f + expf(-af));
      float gg = tanhf(ag);
      float og = 1.f / (1.f + expf(-ao));
      c = fg * c + ig * gg;
      float h = og * tanhf(c);
      // barrier #2: all reads of h_sh for this step done
      __syncthreads();
      h_sh[j] = h;
      outb[(size_t)t * Hh + j] = h;
      if (t == L - 1) lastb[j] = h;
    } else {
      outb[(size_t)t * Hh + j] = 0.f;
    }
  }
}

extern "C" void kernel_launch(void* const* d_in, const int* in_sizes, int n_in,
                              void* d_out, int out_size, void* d_ws, size_t ws_size,
                              hipStream_t stream) {
  const float* x = (const float*)d_in[0];
  const int* mask = (const int*)d_in[1];
  const float* W_ih = (const float*)d_in[2];
  const float* W_hh = (const float*)d_in[3];
  const float* b_ih = (const float*)d_in[4];
  const float* b_hh = (const float*)d_in[5];
  float* out = (float*)d_out;
  char* ws = (char*)d_ws;

  const size_t WT_HH_OFF = 0;
  const size_t WT_HH_BYTES = (size_t)Ss * 64 * G4 * 16;  // 4 MiB
  const size_t WT_IH_OFF = WT_HH_OFF + WT_HH_BYTES;
  const size_t WT_IH_BYTES = (size_t)Ss * 32 * G4 * 16;  // 2 MiB
  const size_t LEN_OFF = WT_IH_OFF + WT_IH_BYTES;
  const size_t LEN_BYTES = 65536;
  const size_t GX_OFF = LEN_OFF + LEN_BYTES;
  const size_t GX_BYTES = (size_t)Bb * Tt * G4 * 4;  // 512 MiB

  float4* wt_hh = (float4*)(ws + WT_HH_OFF);
  float4* wt_ih = (float4*)(ws + WT_IH_OFF);
  int* len = (int*)(ws + LEN_OFF);
  float* gx = (float*)(ws + GX_OFF);
  bool use_gx = ws_size >= GX_OFF + GX_BYTES;

  k_len<<<Bb, 256, 0, stream>>>(mask, len);
  k_tr<<<1536, 256, 0, stream>>>(W_ih, W_hh, wt_hh, wt_ih);
  if (use_gx) {
    k_gx<<<Bb * 16, 256, 0, stream>>>(x, wt_ih, b_ih, b_hh, len, gx);
    k_lstm<true><<<Bb, 256, 0, stream>>>(x, wt_hh, wt_ih, b_ih, b_hh, len, gx, out);
  } else {
    k_lstm<false><<<Bb, 256, 0, stream>>>(x, wt_hh, wt_ih, b_ih, b_hh, len,
                                          (const float*)nullptr, out);
  }
}

// Round 2
// 3529.908 us; speedup vs baseline: 2.8429x; 2.8429x over previous
//
#include <hip/hip_runtime.h>
#include <math.h>

#define Bb 256
#define Tt 512
#define Ii 128
#define Hh 256
#define Ss 4
#define G4 1024  // 4*H gate rows

typedef _Float16 half2t __attribute__((ext_vector_type(2)));
union W16 { uint4 u; half2t h[4]; };

__device__ __forceinline__ float dot8(uint4 w, uint4 hv, float acc) {
  W16 a; a.u = w; W16 b; b.u = hv;
#if __has_builtin(__builtin_amdgcn_fdot2)
  acc = __builtin_amdgcn_fdot2(a.h[0], b.h[0], acc, false);
  acc = __builtin_amdgcn_fdot2(a.h[1], b.h[1], acc, false);
  acc = __builtin_amdgcn_fdot2(a.h[2], b.h[2], acc, false);
  acc = __builtin_amdgcn_fdot2(a.h[3], b.h[3], acc, false);
#else
#pragma unroll
  for (int k = 0; k < 4; k++)
    acc += (float)a.h[k].x * (float)b.h[k].x + (float)a.h[k].y * (float)b.h[k].y;
#endif
  return acc;
}

// ---------------- kernel 1: lengths[b] = max(sum(mask[b,:]), 1) ----------------
__global__ void k_len(const int* __restrict__ mask, int* __restrict__ len) {
  int b = blockIdx.x, tid = threadIdx.x;
  int c = (mask[b * Tt + tid] != 0) + (mask[b * Tt + 256 + tid] != 0);
#pragma unroll
  for (int off = 32; off > 0; off >>= 1) c += __shfl_down(c, off, 64);
  __shared__ int red[4];
  if ((tid & 63) == 0) red[tid >> 6] = c;
  __syncthreads();
  if (tid == 0) {
    int t = red[0] + red[1] + red[2] + red[3];
    len[b] = t < 1 ? 1 : t;
  }
}

// ---------------- kernel 2: weight transforms --------------------------------
// wt_hh16[(s*32+i8)*1024+o] = 8 halfs {W_hh[s][o][8i8..8i8+7]}
// wt_ih  [(s*32+i4)*1024+o] = float4 {W_ih[s][o][4i4..4i4+3]}   (for k_gx)
// wt_ih16[(s*16+i8)*1024+o] = 8 halfs {W_ih[s][o][8i8..8i8+7]}  (fallback path)
__global__ void k_tr(const float* __restrict__ W_ih, const float* __restrict__ W_hh,
                     uint4* __restrict__ wt_hh16, float4* __restrict__ wt_ih,
                     uint4* __restrict__ wt_ih16) {
  int id = blockIdx.x * blockDim.x + threadIdx.x;
  const int NH16 = Ss * 32 * G4;  // 131072
  const int NI4 = Ss * 32 * G4;   // 131072
  const int NI16 = Ss * 16 * G4;  // 65536
  if (id < NH16) {
    int o = id % G4, i8 = (id / G4) % 32, s = id / (G4 * 32);
    const float* src = W_hh + ((size_t)(s * G4 + o)) * Hh + 8 * i8;
    W16 w;
#pragma unroll
    for (int k = 0; k < 4; k++) {
      w.h[k].x = (_Float16)src[2 * k];
      w.h[k].y = (_Float16)src[2 * k + 1];
    }
    wt_hh16[id] = w.u;
  } else if (id < NH16 + NI4) {
    int id2 = id - NH16;
    int o = id2 % G4, i4 = (id2 / G4) % 32, s = id2 / (G4 * 32);
    wt_ih[id2] = *(const float4*)(W_ih + ((size_t)(s * G4 + o)) * Ii + 4 * i4);
  } else if (id < NH16 + NI4 + NI16) {
    int id3 = id - NH16 - NI4;
    int o = id3 % G4, i8 = (id3 / G4) % 16, s = id3 / (G4 * 16);
    const float* src = W_ih + ((size_t)(s * G4 + o)) * Ii + 8 * i8;
    W16 w;
#pragma unroll
    for (int k = 0; k < 4; k++) {
      w.h[k].x = (_Float16)src[2 * k];
      w.h[k].y = (_Float16)src[2 * k + 1];
    }
    wt_ih16[id3] = w.u;
  }
}

// ---------------- kernel 3: gx[b][t][o] = W_ih[seg]@x + b_ih[seg]+b_hh[seg] ----
__global__ __launch_bounds__(256, 2) void k_gx(
    const float* __restrict__ x, const float4* __restrict__ wt_ih,
    const float* __restrict__ b_ih, const float* __restrict__ b_hh,
    const int* __restrict__ len, float* __restrict__ gx) {
  const int b = blockIdx.x >> 4;
  const int t0 = (blockIdx.x & 15) * 32;
  const int tid = threadIdx.x;
  const int L = len[b];
  if (t0 >= L) return;  // gx never read for t >= L
  __shared__ __align__(16) float xs[32 * Ii];
  __shared__ int segt[32];
  float4* xs4 = (float4*)xs;
  const float4* xsrc = (const float4*)(x + ((size_t)b * Tt + t0) * Ii);
  for (int f = tid; f < 32 * 32; f += 256) xs4[f] = xsrc[f];
  if (tid < 32) {
    int s = (t0 + tid) * Ss / L;
    segt[tid] = s > Ss - 1 ? Ss - 1 : s;
  }
  __syncthreads();
  const int s_lo = segt[0];
  const int s_hi = segt[31];
  for (int s = s_lo; s <= s_hi; s++) {
    float acc[4][32];
#pragma unroll
    for (int g = 0; g < 4; g++)
#pragma unroll
      for (int t = 0; t < 32; t++) acc[g][t] = 0.f;
    const float4* wb = wt_ih + (size_t)s * 32 * G4 + tid;
    for (int i4 = 0; i4 < 32; i4++) {
      float4 w0 = wb[i4 * G4];
      float4 w1 = wb[i4 * G4 + 256];
      float4 w2 = wb[i4 * G4 + 512];
      float4 w3 = wb[i4 * G4 + 768];
#pragma unroll
      for (int t = 0; t < 32; t++) {
        float4 hv = xs4[t * 32 + i4];
        acc[0][t] += w0.x * hv.x + w0.y * hv.y + w0.z * hv.z + w0.w * hv.w;
        acc[1][t] += w1.x * hv.x + w1.y * hv.y + w1.z * hv.z + w1.w * hv.w;
        acc[2][t] += w2.x * hv.x + w2.y * hv.y + w2.z * hv.z + w2.w * hv.w;
        acc[3][t] += w3.x * hv.x + w3.y * hv.y + w3.z * hv.z + w3.w * hv.w;
      }
    }
    float bsum[4];
#pragma unroll
    for (int g = 0; g < 4; g++)
      bsum[g] = b_ih[s * G4 + g * 256 + tid] + b_hh[s * G4 + g * 256 + tid];
#pragma unroll
    for (int t = 0; t < 32; t++) {
      if (segt[t] == s) {
        size_t base = ((size_t)b * Tt + t0 + t) * G4 + tid;
#pragma unroll
        for (int g = 0; g < 4; g++) gx[base + g * 256] = acc[g][t] + bsum[g];
      }
    }
  }
}

// ---------------- kernel 4: recurrence, fp16 weights, 512 threads --------------
// Thread (u, pr): pr=0 owns rows u (i) and u+512 (g); pr=1 rows u+256 (f), u+768 (o).
// pr=1 pushes sigmoid(f),sigmoid(o) through LDS; pr=0 keeps c and writes h.
template <bool USE_GX>
__global__ __launch_bounds__(512, 1) void k_lstm16(
    const float* __restrict__ x, const uint4* __restrict__ wt_hh16,
    const uint4* __restrict__ wt_ih16, const float* __restrict__ b_ih,
    const float* __restrict__ b_hh, const int* __restrict__ len,
    const float* __restrict__ gx, float* __restrict__ out) {
  const int b = blockIdx.x;
  const int tid = threadIdx.x;
  const int u = tid & 255;
  const int pr = tid >> 8;
  const int r0 = u + pr * 256;  // i-row (pr0) or f-row (pr1)
  const int r1 = r0 + 512;      // g-row (pr0) or o-row (pr1)
  __shared__ __align__(16) _Float16 h_h[Hh];
  __shared__ __align__(16) _Float16 x_h[Ii];
  __shared__ float f_sh[Hh];
  __shared__ float o_sh[Hh];
  if (pr == 0) h_h[u] = (_Float16)0.f;
  float c = 0.f;
  const int L = len[b];
  float* outb = out + (size_t)b * Tt * Hh;
  float* lastb = out + (size_t)Bb * Tt * Hh + (size_t)b * Hh;
  const uint4* h4 = (const uint4*)h_h;
  const uint4* x4 = (const uint4*)x_h;
  for (int t = 0; t < Tt; t++) {
    if (t < L) {  // block-uniform
      int s = t * Ss / L;
      if (s > Ss - 1) s = Ss - 1;
      float a0, a1;
      if (USE_GX) {
        const float* g = gx + ((size_t)b * Tt + t) * G4;
        a0 = g[r0];
        a1 = g[r1];
      } else {
        if (tid < 128) x_h[tid] = (_Float16)x[((size_t)b * Tt + t) * Ii + tid];
        a0 = b_ih[s * G4 + r0] + b_hh[s * G4 + r0];
        a1 = b_ih[s * G4 + r1] + b_hh[s * G4 + r1];
      }
      __syncthreads();  // B1: prev h_h (and x_h) visible
      const uint4* wb = wt_hh16 + (size_t)s * 32 * G4;
#pragma unroll 8
      for (int i8 = 0; i8 < 32; i8++) {
        uint4 hv = h4[i8];  // wave-uniform LDS broadcast
        a0 = dot8(wb[i8 * G4 + r0], hv, a0);
        a1 = dot8(wb[i8 * G4 + r1], hv, a1);
      }
      if (!USE_GX) {
        const uint4* wbi = wt_ih16 + (size_t)s * 16 * G4;
#pragma unroll
        for (int i8 = 0; i8 < 16; i8++) {
          uint4 xv = x4[i8];
          a0 = dot8(wbi[i8 * G4 + r0], xv, a0);
          a1 = dot8(wbi[i8 * G4 + r1], xv, a1);
        }
      }
      if (pr == 1) {
        f_sh[u] = 1.f / (1.f + expf(-a0));
        o_sh[u] = 1.f / (1.f + expf(-a1));
      }
      __syncthreads();  // B2: dot reads done; f/o visible
      if (pr == 0) {
        float ig = 1.f / (1.f + expf(-a0));
        float gg = tanhf(a1);
        c = f_sh[u] * c + ig * gg;
        float h = o_sh[u] * tanhf(c);
        h_h[u] = (_Float16)h;
        outb[(size_t)t * Hh + u] = h;
        if (t == L - 1) lastb[u] = h;
      }
    } else {
      if (pr == 0) outb[(size_t)t * Hh + u] = 0.f;
    }
  }
}

extern "C" void kernel_launch(void* const* d_in, const int* in_sizes, int n_in,
                              void* d_out, int out_size, void* d_ws, size_t ws_size,
                              hipStream_t stream) {
  const float* x = (const float*)d_in[0];
  const int* mask = (const int*)d_in[1];
  const float* W_ih = (const float*)d_in[2];
  const float* W_hh = (const float*)d_in[3];
  const float* b_ih = (const float*)d_in[4];
  const float* b_hh = (const float*)d_in[5];
  float* out = (float*)d_out;
  char* ws = (char*)d_ws;

  const size_t HH16_OFF = 0;
  const size_t HH16_BYTES = (size_t)Ss * 32 * G4 * 16;  // 2 MiB
  const size_t IH4_OFF = HH16_OFF + HH16_BYTES;
  const size_t IH4_BYTES = (size_t)Ss * 32 * G4 * 16;   // 2 MiB
  const size_t IH16_OFF = IH4_OFF + IH4_BYTES;
  const size_t IH16_BYTES = (size_t)Ss * 16 * G4 * 16;  // 1 MiB
  const size_t LEN_OFF = IH16_OFF + IH16_BYTES;
  const size_t LEN_BYTES = 65536;
  const size_t GX_OFF = LEN_OFF + LEN_BYTES;
  const size_t GX_BYTES = (size_t)Bb * Tt * G4 * 4;     // 512 MiB

  uint4* wt_hh16 = (uint4*)(ws + HH16_OFF);
  float4* wt_ih = (float4*)(ws + IH4_OFF);
  uint4* wt_ih16 = (uint4*)(ws + IH16_OFF);
  int* len = (int*)(ws + LEN_OFF);
  float* gx = (float*)(ws + GX_OFF);
  bool use_gx = ws_size >= GX_OFF + GX_BYTES;

  k_len<<<Bb, 256, 0, stream>>>(mask, len);
  k_tr<<<1280, 256, 0, stream>>>(W_ih, W_hh, wt_hh16, wt_ih, wt_ih16);
  if (use_gx) {
    k_gx<<<Bb * 16, 256, 0, stream>>>(x, wt_ih, b_ih, b_hh, len, gx);
    k_lstm16<true><<<Bb, 512, 0, stream>>>(x, wt_hh16, wt_ih16, b_ih, b_hh, len,
                                           gx, out);
  } else {
    k_lstm16<false><<<Bb, 512, 0, stream>>>(x, wt_hh16, wt_ih16, b_ih, b_hh, len,
                                            (const float*)nullptr, out);
  }
}